// Round 2
// baseline (46100.122 us; speedup 1.0000x reference)
//
#include <hip/hip_runtime.h>
#include <cstdint>
#include <cstddef>

#define NSTEPS 1024
#define TCHUNK 128
#define NCHUNK 8
#define BATCH 32
#define IDIM 128
#define HDIM 512
#define GDIM 2048
#define ODIM 10
#define NBLK 256
#define NGRP 16   // barrier groups
#define GSZ 16    // blocks per group

__device__ __forceinline__ float agent_load_f(const float* p) {
  return __hip_atomic_load(p, __ATOMIC_RELAXED, __HIP_MEMORY_SCOPE_AGENT);
}
__device__ __forceinline__ void agent_store_f(float* p, float v) {
  __hip_atomic_store(p, v, __ATOMIC_RELAXED, __HIP_MEMORY_SCOPE_AGENT);
}

// ---------------------------------------------------------------------------
// proj: P[tt][n][b] = sum_k X[tt*32+b][k] * W[n][k] + bias[n]
// X: [TCHUNK*BATCH][K] row-major, W: [GDIM][K] row-major, P: [TCHUNK][GDIM][BATCH]
// ---------------------------------------------------------------------------
template<int K>
__launch_bounds__(256, 2)
__global__ void proj_kernel(const float* __restrict__ X,
                            const float* __restrict__ W,
                            const float* __restrict__ bias,
                            float* __restrict__ P) {
  __shared__ float Xs[8][132];
  __shared__ float Ws[8][132];
  const int tid = threadIdx.x;
  const int n0 = blockIdx.x * 128;
  const int m0 = blockIdx.y * 128;
  const int tx = tid & 15, ty = tid >> 4;
  const int lm = tid >> 1;
  const int kq = (tid & 1) * 4;
  float acc[8][8];
#pragma unroll
  for (int i = 0; i < 8; ++i)
#pragma unroll
    for (int j = 0; j < 8; ++j) acc[i][j] = 0.f;

  for (int k0 = 0; k0 < K; k0 += 8) {
    const float4 xv = *(const float4*)&X[(size_t)(m0 + lm) * K + k0 + kq];
    const float4 wv = *(const float4*)&W[(size_t)(n0 + lm) * K + k0 + kq];
    __syncthreads();
    Xs[kq + 0][lm] = xv.x; Xs[kq + 1][lm] = xv.y; Xs[kq + 2][lm] = xv.z; Xs[kq + 3][lm] = xv.w;
    Ws[kq + 0][lm] = wv.x; Ws[kq + 1][lm] = wv.y; Ws[kq + 2][lm] = wv.z; Ws[kq + 3][lm] = wv.w;
    __syncthreads();
#pragma unroll
    for (int kk = 0; kk < 8; ++kk) {
      float a[8], b[8];
      *(float4*)&a[0] = *(const float4*)&Xs[kk][ty * 8];
      *(float4*)&a[4] = *(const float4*)&Xs[kk][ty * 8 + 4];
      *(float4*)&b[0] = *(const float4*)&Ws[kk][tx * 8];
      *(float4*)&b[4] = *(const float4*)&Ws[kk][tx * 8 + 4];
#pragma unroll
      for (int i = 0; i < 8; ++i)
#pragma unroll
        for (int j = 0; j < 8; ++j) acc[i][j] += a[i] * b[j];
    }
  }
  const int mb = m0 + ty * 8;      // 8-aligned -> all 8 i share one t
  const int t  = mb >> 5;
  const int b0 = mb & 31;
#pragma unroll
  for (int j = 0; j < 8; ++j) {
    const int n = n0 + tx * 8 + j;
    const float bj = bias[n];
    float* dst = &P[((size_t)t * GDIM + n) * BATCH + b0];
#pragma unroll
    for (int i = 0; i < 8; ++i) dst[i] = acc[i][j] + bj;
  }
}

// ---------------------------------------------------------------------------
// scan: persistent LSTM recurrence over one T-chunk. 256 blocks, 1 block/CU.
// h exchange via agent-scope (sc1) accesses -> no L2 flush/invalidate.
// Two-level grid barrier: 16 groups x 16 blocks -> root counter.
// ---------------------------------------------------------------------------
__launch_bounds__(256, 1)
__global__ void scan_kernel(const float* __restrict__ xp,    // [TCHUNK][GDIM][BATCH]
                            const float* __restrict__ Whh,   // [GDIM][HDIM]
                            float* __restrict__ hout,        // [TCHUNK][BATCH][HDIM]
                            float* __restrict__ hcur,        // [2][HDIM][BATCH] ping-pong
                            float* __restrict__ ccur,        // [HDIM][BATCH]
                            unsigned* __restrict__ bar,      // [NGRP*32] grp | +512: root
                            int phase0, int first) {
  __shared__ float h_s[HDIM][BATCH];   // 64KB, k-major
  __shared__ float W_s[HDIM][8];       // 16KB, k-major
  __shared__ float red[16][256];       // 16KB, k-split partials
  __shared__ float gate_s[8][BATCH];   // 1KB

  const int tid = threadIdx.x;
  const int bid = blockIdx.x;
  unsigned* grpbar = bar + (bid >> 4) * 32;   // 128B-spaced per-group lines
  unsigned* rootbar = bar + 512;

  // Load this block's 8 W_hh rows once; reused for all TCHUNK steps.
#pragma unroll
  for (int r = 0; r < 8; ++r) {
    const int row_g = (r >> 1) * HDIM + bid * 2 + (r & 1);
    for (int k = tid; k < HDIM; k += 256) W_s[k][r] = Whh[(size_t)row_g * HDIM + k];
  }

  // compute-phase role: thread = (p, s); p -> 4b x 4r tile, s -> 32-wide K slice
  const int p  = tid & 15;
  const int s  = tid >> 4;
  const int pb = (p & 7) * 4;
  const int pr = (p >> 3) * 4;
  // reduce-phase role: one gate pre-activation per thread
  const int out_r = tid >> 5;
  const int out_b = tid & 31;
  // update-phase role (tid < 64): one (hidx, b) cell
  const int uj = tid >> 5;
  const int ub = tid & 31;
  const int hidx = bid * 2 + uj;

  float c_st = 0.f;
  if (!first && tid < 64) c_st = ccur[hidx * BATCH + ub];

  unsigned phase = (unsigned)phase0;
  __syncthreads();

  for (int tt = 0; tt < TCHUNK; ++tt) {
    const int rp = tt & 1;
    // ---- stage h_prev into LDS via agent-scope (LLC) loads, conflict-free ----
    const float* src = hcur + (size_t)rp * HDIM * BATCH;
#pragma unroll
    for (int i = 0; i < 64; ++i) {
      const int idx = tid + 256 * i;            // word index, 16384 total
      h_s[idx >> 5][idx & 31] = agent_load_f(src + idx);
    }
    __syncthreads();

    // ---- gates partials: acc[r][b] over this thread's 32-wide K slice ----
    float acc[4][4];
#pragma unroll
    for (int i = 0; i < 4; ++i)
#pragma unroll
      for (int j = 0; j < 4; ++j) acc[i][j] = 0.f;
    const int kbase = s * 32;
#pragma unroll
    for (int kk = 0; kk < 32; ++kk) {
      const float4 hv = *(const float4*)&h_s[kbase + kk][pb];
      const float4 wv = *(const float4*)&W_s[kbase + kk][pr];
      acc[0][0] += wv.x * hv.x; acc[0][1] += wv.x * hv.y; acc[0][2] += wv.x * hv.z; acc[0][3] += wv.x * hv.w;
      acc[1][0] += wv.y * hv.x; acc[1][1] += wv.y * hv.y; acc[1][2] += wv.y * hv.z; acc[1][3] += wv.y * hv.w;
      acc[2][0] += wv.z * hv.x; acc[2][1] += wv.z * hv.y; acc[2][2] += wv.z * hv.z; acc[2][3] += wv.z * hv.w;
      acc[3][0] += wv.w * hv.x; acc[3][1] += wv.w * hv.y; acc[3][2] += wv.w * hv.z; acc[3][3] += wv.w * hv.w;
    }
#pragma unroll
    for (int ri = 0; ri < 4; ++ri)
      *(float4*)&red[s][(pr + ri) * 32 + pb] =
          make_float4(acc[ri][0], acc[ri][1], acc[ri][2], acc[ri][3]);
    __syncthreads();

    // ---- reduce K-split partials, add xp, apply activation ----
    float pre = 0.f;
#pragma unroll
    for (int s2 = 0; s2 < 16; ++s2) pre += red[s2][tid];
    const int q = out_r >> 1;
    const int row_g = q * HDIM + bid * 2 + (out_r & 1);
    pre += xp[((size_t)tt * GDIM + row_g) * BATCH + out_b];
    const float act = (q == 2) ? tanhf(pre) : 1.f / (1.f + __expf(-pre));
    gate_s[out_r][out_b] = act;
    __syncthreads();

    // ---- c/h update (wave 0 only; 2 hidx x 32 b) ----
    if (tid < 64) {
      const float ig = gate_s[0 + uj][ub];
      const float fg = gate_s[2 + uj][ub];
      const float gg = gate_s[4 + uj][ub];
      const float og = gate_s[6 + uj][ub];
      c_st = fg * c_st + ig * gg;
      const float h = og * tanhf(c_st);
      agent_store_f(hcur + (size_t)(1 - rp) * HDIM * BATCH + hidx * BATCH + ub, h);
      hout[(size_t)tt * BATCH * HDIM + ub * HDIM + hidx] = h;   // plain, cached
      // wave-wide drain: h stores are at LLC before we signal arrival
      asm volatile("s_waitcnt vmcnt(0)" ::: "memory");
    }
    __syncthreads();

    // ---- two-level grid barrier (monotonic counters, agent scope) ----
    if (tid == 0) {
      ++phase;
      const unsigned old = __hip_atomic_fetch_add(grpbar, 1u,
                              __ATOMIC_RELAXED, __HIP_MEMORY_SCOPE_AGENT);
      if (old == phase * (unsigned)GSZ - 1u)    // last arrival in group
        __hip_atomic_fetch_add(rootbar, 1u,
                              __ATOMIC_RELAXED, __HIP_MEMORY_SCOPE_AGENT);
      while (__hip_atomic_load(rootbar, __ATOMIC_RELAXED,
                               __HIP_MEMORY_SCOPE_AGENT) < phase * (unsigned)NGRP)
        __builtin_amdgcn_s_sleep(2);
      asm volatile("" ::: "memory");
    } else {
      ++phase;
    }
    __syncthreads();
  }
  if (tid < 64) ccur[hidx * BATCH + ub] = c_st;
}

// ---------------------------------------------------------------------------
// head: logits = h2 @ W3^T + b3 ; softmax over 10. One wave per row.
// ---------------------------------------------------------------------------
__launch_bounds__(256, 2)
__global__ void head_kernel(const float* __restrict__ h2,   // [rows][HDIM]
                            const float* __restrict__ W3,   // [ODIM][HDIM]
                            const float* __restrict__ b3,
                            float* __restrict__ outp) {     // [rows][ODIM]
  const int tid = threadIdx.x;
  const int lane = tid & 63;
  const int wv = tid >> 6;
  const int row = blockIdx.x * 4 + wv;
  const float* hrow = &h2[(size_t)row * HDIM];
  float hreg[8];
  *(float4*)&hreg[0] = *(const float4*)&hrow[lane * 8];
  *(float4*)&hreg[4] = *(const float4*)&hrow[lane * 8 + 4];
  float logit[ODIM];
#pragma unroll
  for (int o = 0; o < ODIM; ++o) {
    const float* wrow = &W3[o * HDIM + lane * 8];
    float w[8];
    *(float4*)&w[0] = *(const float4*)&wrow[0];
    *(float4*)&w[4] = *(const float4*)&wrow[4];
    float pp = 0.f;
#pragma unroll
    for (int j = 0; j < 8; ++j) pp += hreg[j] * w[j];
#pragma unroll
    for (int off = 32; off > 0; off >>= 1) pp += __shfl_xor(pp, off);
    logit[o] = pp + b3[o];
  }
  float m = logit[0];
#pragma unroll
  for (int o = 1; o < ODIM; ++o) m = fmaxf(m, logit[o]);
  float ssum = 0.f;
#pragma unroll
  for (int o = 0; o < ODIM; ++o) { logit[o] = __expf(logit[o] - m); ssum += logit[o]; }
  const float inv = 1.f / ssum;
  if (lane == 0) {
    float* dst = &outp[(size_t)row * ODIM];
#pragma unroll
    for (int o = 0; o < ODIM; ++o) dst[o] = logit[o] * inv;
  }
}

// ---------------------------------------------------------------------------
extern "C" void kernel_launch(void* const* d_in, const int* in_sizes, int n_in,
                              void* d_out, int out_size, void* d_ws, size_t ws_size,
                              hipStream_t stream) {
  const float* data  = (const float*)d_in[0];
  const float* W_ih1 = (const float*)d_in[1];
  const float* W_hh1 = (const float*)d_in[2];
  const float* b1    = (const float*)d_in[3];
  const float* W_ih2 = (const float*)d_in[4];
  const float* W_hh2 = (const float*)d_in[5];
  const float* b2    = (const float*)d_in[6];
  const float* W3    = (const float*)d_in[7];
  const float* b3    = (const float*)d_in[8];
  float* outp = (float*)d_out;

  char* ws = (char*)d_ws;
  size_t off = 0;
  float* xp    = (float*)(ws + off); off += (size_t)TCHUNK * GDIM * BATCH * 4;   // 32MB
  float* h1c   = (float*)(ws + off); off += (size_t)TCHUNK * BATCH * HDIM * 4;   // 8MB
  float* h2c   = (float*)(ws + off); off += (size_t)TCHUNK * BATCH * HDIM * 4;   // 8MB
  float* hcur1 = (float*)(ws + off); off += 2 * HDIM * BATCH * 4;
  float* hcur2 = (float*)(ws + off); off += 2 * HDIM * BATCH * 4;
  float* ccur1 = (float*)(ws + off); off += HDIM * BATCH * 4;
  float* ccur2 = (float*)(ws + off); off += HDIM * BATCH * 4;
  unsigned* bar1 = (unsigned*)(ws + off); off += 4096;   // 16 grp lines + root
  unsigned* bar2 = (unsigned*)(ws + off); off += 4096;
  if (off > ws_size) return;  // workspace too small: bail (output stays invalid)

  hipMemsetAsync(hcur1, 0, HDIM * BATCH * 4, stream);   // parity-0 buffer = h0 = 0
  hipMemsetAsync(hcur2, 0, HDIM * BATCH * 4, stream);
  hipMemsetAsync(bar1, 0, 4096, stream);
  hipMemsetAsync(bar2, 0, 4096, stream);

  const dim3 pgrid(GDIM / 128, (TCHUNK * BATCH) / 128);
  for (int c = 0; c < NCHUNK; ++c) {
    const float* xin = data + (size_t)c * TCHUNK * BATCH * IDIM;
    proj_kernel<IDIM><<<pgrid, 256, 0, stream>>>(xin, W_ih1, b1, xp);
    scan_kernel<<<NBLK, 256, 0, stream>>>(xp, W_hh1, h1c, hcur1, ccur1, bar1,
                                          c * TCHUNK, c == 0);
    proj_kernel<HDIM><<<pgrid, 256, 0, stream>>>(h1c, W_ih2, b2, xp);
    scan_kernel<<<NBLK, 256, 0, stream>>>(xp, W_hh2, h2c, hcur2, ccur2, bar2,
                                          c * TCHUNK, c == 0);
    head_kernel<<<(TCHUNK * BATCH) / 4, 256, 0, stream>>>(
        h2c, W3, b3, outp + (size_t)c * TCHUNK * BATCH * ODIM);
  }
}

// Round 4
// 10227.147 us; speedup vs baseline: 4.5076x; 4.5076x over previous
//
#include <hip/hip_runtime.h>
#include <cstdint>
#include <cstddef>

#define TCHUNK 128
#define NCHUNK 8
#define BATCH 32
#define IDIM 128
#define HDIM 512
#define GDIM 2048
#define ODIM 10
#define NBLK 256
#define XPSTEP (GDIM * BATCH)

typedef float f4 __attribute__((ext_vector_type(4)));

// ---- LLC-coherent (sc0 sc1) primitives: correct on any XCD placement ----
__device__ __forceinline__ void llc_load4x2(const float* p0, const float* p1,
                                            f4& a, f4& b) {
  asm volatile("global_load_dwordx4 %0, %2, off sc0 sc1\n\t"
               "global_load_dwordx4 %1, %3, off sc0 sc1\n\t"
               "s_waitcnt vmcnt(0)"
               : "=&v"(a), "=&v"(b) : "v"(p0), "v"(p1) : "memory");
}
__device__ __forceinline__ void llc_store(float* p, float v) {
  asm volatile("global_store_dword %0, %1, off sc0 sc1" :: "v"(p), "v"(v) : "memory");
}
__device__ __forceinline__ void llc_store_u32(unsigned* p, unsigned v) {
  asm volatile("global_store_dword %0, %1, off sc0 sc1" :: "v"(p), "v"(v) : "memory");
}
__device__ __forceinline__ unsigned llc_load_u32(const unsigned* p) {
  unsigned v;
  asm volatile("global_load_dword %0, %1, off sc0 sc1\n\ts_waitcnt vmcnt(0)"
               : "=v"(v) : "v"(p) : "memory");
  return v;
}

// quad (4-lane) butterfly sum via DPP quad_perm — pure VALU, no LDS pipe
__device__ __forceinline__ float quad_sum(float x) {
  int t = __builtin_amdgcn_update_dpp(0, __float_as_int(x), 0xB1, 0xF, 0xF, true);
  x += __int_as_float(t);
  t = __builtin_amdgcn_update_dpp(0, __float_as_int(x), 0x4E, 0xF, 0xF, true);
  x += __int_as_float(t);
  return x;
}

// ---------------------------------------------------------------------------
// proj: P[tt][n][b] = sum_k X[tt*32+b][k] * W[n][k] + bias[n]
// ---------------------------------------------------------------------------
template<int K>
__launch_bounds__(256, 2)
__global__ void proj_kernel(const float* __restrict__ X,
                            const float* __restrict__ W,
                            const float* __restrict__ bias,
                            float* __restrict__ P) {
  __shared__ float Xs[8][132];
  __shared__ float Ws[8][132];
  const int tid = threadIdx.x;
  const int n0 = blockIdx.x * 128;
  const int m0 = blockIdx.y * 128;
  const int tx = tid & 15, ty = tid >> 4;
  const int lm = tid >> 1;
  const int kq = (tid & 1) * 4;
  float acc[8][8];
#pragma unroll
  for (int i = 0; i < 8; ++i)
#pragma unroll
    for (int j = 0; j < 8; ++j) acc[i][j] = 0.f;

  for (int k0 = 0; k0 < K; k0 += 8) {
    const float4 xv = *(const float4*)&X[(size_t)(m0 + lm) * K + k0 + kq];
    const float4 wv = *(const float4*)&W[(size_t)(n0 + lm) * K + k0 + kq];
    __syncthreads();
    Xs[kq + 0][lm] = xv.x; Xs[kq + 1][lm] = xv.y; Xs[kq + 2][lm] = xv.z; Xs[kq + 3][lm] = xv.w;
    Ws[kq + 0][lm] = wv.x; Ws[kq + 1][lm] = wv.y; Ws[kq + 2][lm] = wv.z; Ws[kq + 3][lm] = wv.w;
    __syncthreads();
#pragma unroll
    for (int kk = 0; kk < 8; ++kk) {
      float a[8], b[8];
      *(float4*)&a[0] = *(const float4*)&Xs[kk][ty * 8];
      *(float4*)&a[4] = *(const float4*)&Xs[kk][ty * 8 + 4];
      *(float4*)&b[0] = *(const float4*)&Ws[kk][tx * 8];
      *(float4*)&b[4] = *(const float4*)&Ws[kk][tx * 8 + 4];
#pragma unroll
      for (int i = 0; i < 8; ++i)
#pragma unroll
        for (int j = 0; j < 8; ++j) acc[i][j] += a[i] * b[j];
    }
  }
  const int mb = m0 + ty * 8;
  const int t  = mb >> 5;
  const int b0 = mb & 31;
#pragma unroll
  for (int j = 0; j < 8; ++j) {
    const int n = n0 + tx * 8 + j;
    const float bj = bias[n];
    float* dst = &P[((size_t)t * GDIM + n) * BATCH + b0];
#pragma unroll
    for (int i = 0; i < 8; ++i) dst[i] = acc[i][j] + bj;
  }
}

// ---------------------------------------------------------------------------
// scan: logical-group LSTM recurrence. 256 blocks, 1/CU (LDS pad).
// Group g = bid&7 (32 blocks) owns batches 4g..4g+3. Block rank = bid>>3
// owns h-slots rank*16..+15 (x 4 gates = 64 W_hh rows, held in VGPRs).
// Exchange + flags via LLC (sc0 sc1) — placement-independent.
// ---------------------------------------------------------------------------
__launch_bounds__(256, 1)
__global__ void scan_kernel(const float* __restrict__ xp,    // [TCHUNK][GDIM][BATCH]
                            const float* __restrict__ Whh,   // [GDIM][HDIM]
                            float* __restrict__ hout,        // [TCHUNK][BATCH][HDIM]
                            float* __restrict__ hx,          // [8][2][512*4] ping-pong
                            float* __restrict__ ccur,        // [BATCH][HDIM]
                            unsigned* __restrict__ flg,      // [8][64] flag lines
                            int phase0, int first) {
  __shared__ float h_s[2048];       // h[k][b], k XOR-permuted
  __shared__ float red[1024];       // cross-wave partials
  __shared__ float gate_s[256];
  __shared__ float lds_pad[22528];  // 88KB: force 1 block/CU

  const int tid = threadIdx.x;
  const int bid = blockIdx.x;
  const int g = bid & 7, rank = bid >> 3;
  const int w = tid >> 6, l = tid & 63;
  const int rq = l >> 2, s4 = l & 3;

  float* hxg = hx + g * 4096;
  unsigned* flgg = flg + g * 64;

  // ---- W_hh slice into registers: rows 4rq..4rq+3, k in [kbase,kbase+32) ----
  const int kbase = 128 * w + 32 * s4;
  const int m = (4 * w + s4) & 15;          // h-perm key for this k-slice
  const int hbase = 4 * kbase;
  float wreg[4][32];
#pragma unroll
  for (int r = 0; r < 4; ++r) {
    const int rl = 4 * rq + r;
    const int grow = (rl >> 4) * HDIM + rank * 16 + (rl & 15);
    const float* wp = &Whh[(size_t)grow * HDIM + kbase];
#pragma unroll
    for (int q8 = 0; q8 < 8; ++q8) {
      const f4 wv = *(const f4*)&wp[q8 * 4];
      wreg[r][q8 * 4 + 0] = wv.x; wreg[r][q8 * 4 + 1] = wv.y;
      wreg[r][q8 * 4 + 2] = wv.z; wreg[r][q8 * 4 + 3] = wv.w;
    }
  }

  // final-reduce cell (one per thread): rl = tid>>2, b = tid&3, gate = tid>>6
  const int rl_c = tid >> 2, b_c = tid & 3;
  const size_t xpoff = (size_t)((tid >> 6) * HDIM + rank * 16 + (rl_c & 15)) * BATCH
                       + g * 4 + b_c;
  // update cell (wave 0): j = l>>2, b = l&3
  const int jj = l >> 2, bb = l & 3;

  float c_st = 0.f;
  if (!first && w == 0) c_st = ccur[(size_t)(g * 4 + bb) * HDIM + rank * 16 + jj];

  // stage group h (8KB) from LLC into LDS, XOR-permuted layout
  auto stage_h = [&](int pp) {
    const float* hp = hxg + pp * 2048;
    f4 a, b;
    llc_load4x2(hp + 8 * tid, hp + 8 * tid + 4, a, b);
    const int mm = (tid >> 4) & 15;           // (2*tid)>>5
    *(f4*)&h_s[4 * ((2 * tid) ^ mm)] = a;
    *(f4*)&h_s[4 * ((2 * tid + 1) ^ mm)] = b;
  };

  stage_h(0);
  __syncthreads();

  for (int tt = 0; tt < TCHUNK; ++tt) {
    const float xpv = xp[(size_t)tt * XPSTEP + xpoff];  // prefetch (plain, cached)

    // ---- partials: 4 rows x 4 batches over this thread's 32-k slice ----
    float acc[4][4];
#pragma unroll
    for (int r = 0; r < 4; ++r)
#pragma unroll
      for (int b = 0; b < 4; ++b) acc[r][b] = 0.f;
#pragma unroll
    for (int idx = 0; idx < 32; ++idx) {
      const f4 hv = *(const f4*)&h_s[hbase + 4 * (idx ^ m)];
#pragma unroll
      for (int r = 0; r < 4; ++r) {
        acc[r][0] += wreg[r][idx] * hv.x;
        acc[r][1] += wreg[r][idx] * hv.y;
        acc[r][2] += wreg[r][idx] * hv.z;
        acc[r][3] += wreg[r][idx] * hv.w;
      }
    }
    // ---- in-quad butterfly over the 4 k-slices (DPP, no LDS) ----
#pragma unroll
    for (int r = 0; r < 4; ++r)
#pragma unroll
      for (int b = 0; b < 4; ++b) acc[r][b] = quad_sum(acc[r][b]);
    // lane s4 takes row r = s4 (compile-time cndmask tree)
    f4 outv;
#pragma unroll
    for (int b = 0; b < 4; ++b) {
      const float v01 = (s4 & 1) ? acc[1][b] : acc[0][b];
      const float v23 = (s4 & 1) ? acc[3][b] : acc[2][b];
      outv[b] = (s4 & 2) ? v23 : v01;
    }
    *(f4*)&red[w * 256 + 4 * l] = outv;
    __syncthreads();

    // ---- cross-wave reduce + xp + activation (1 cell/thread) ----
    const float pre = red[tid] + red[256 + tid] + red[512 + tid] + red[768 + tid] + xpv;
    gate_s[tid] = (w == 2) ? tanhf(pre) : 1.f / (1.f + __expf(-pre));
    __syncthreads();

    // ---- c/h update + exchange + flag + poll (wave 0) ----
    const int wp_ = (tt + 1) & 1;
    const unsigned ph = (unsigned)(phase0 + tt + 1);
    if (w == 0) {
      const float ig = gate_s[l];
      const float fg = gate_s[64 + l];
      const float gg = gate_s[128 + l];
      const float og = gate_s[192 + l];
      c_st = fg * c_st + ig * gg;
      const float hval = og * tanhf(c_st);
      const int slot = rank * 16 + jj;
      llc_store(hxg + wp_ * 2048 + 4 * slot + bb, hval);
      hout[(size_t)tt * (BATCH * HDIM) + (size_t)(g * 4 + bb) * HDIM + slot] = hval;
      asm volatile("s_waitcnt vmcnt(0)" ::: "memory");   // h at LLC before flag
      if (tid == 0) llc_store_u32(flgg + rank, ph);
      const unsigned* fp = flgg + (l & 31);
      while (true) {
        const unsigned fv = llc_load_u32(fp);
        if (__all((int)(fv >= ph))) break;
        __builtin_amdgcn_s_sleep(2);
      }
    }
    __syncthreads();
    stage_h(wp_);
    __syncthreads();
  }
  if (w == 0) ccur[(size_t)(g * 4 + bb) * HDIM + rank * 16 + jj] = c_st;
  if (__float_as_uint(c_st) == 0xDEADBEEFu) lds_pad[tid] = c_st;  // keep pad alive
}

// ---------------------------------------------------------------------------
// head: logits = h2 @ W3^T + b3 ; softmax over 10. One wave per row.
// ---------------------------------------------------------------------------
__launch_bounds__(256, 2)
__global__ void head_kernel(const float* __restrict__ h2,
                            const float* __restrict__ W3,
                            const float* __restrict__ b3,
                            float* __restrict__ outp) {
  const int tid = threadIdx.x;
  const int lane = tid & 63;
  const int wv = tid >> 6;
  const int row = blockIdx.x * 4 + wv;
  const float* hrow = &h2[(size_t)row * HDIM];
  float hreg[8];
  *(float4*)&hreg[0] = *(const float4*)&hrow[lane * 8];
  *(float4*)&hreg[4] = *(const float4*)&hrow[lane * 8 + 4];
  float logit[ODIM];
#pragma unroll
  for (int o = 0; o < ODIM; ++o) {
    const float* wrow = &W3[o * HDIM + lane * 8];
    float w[8];
    *(float4*)&w[0] = *(const float4*)&wrow[0];
    *(float4*)&w[4] = *(const float4*)&wrow[4];
    float pp = 0.f;
#pragma unroll
    for (int j = 0; j < 8; ++j) pp += hreg[j] * w[j];
#pragma unroll
    for (int off = 32; off > 0; off >>= 1) pp += __shfl_xor(pp, off);
    logit[o] = pp + b3[o];
  }
  float mx = logit[0];
#pragma unroll
  for (int o = 1; o < ODIM; ++o) mx = fmaxf(mx, logit[o]);
  float ssum = 0.f;
#pragma unroll
  for (int o = 0; o < ODIM; ++o) { logit[o] = __expf(logit[o] - mx); ssum += logit[o]; }
  const float inv = 1.f / ssum;
  if (lane == 0) {
    float* dst = &outp[(size_t)row * ODIM];
#pragma unroll
    for (int o = 0; o < ODIM; ++o) dst[o] = logit[o] * inv;
  }
}

// ---------------------------------------------------------------------------
extern "C" void kernel_launch(void* const* d_in, const int* in_sizes, int n_in,
                              void* d_out, int out_size, void* d_ws, size_t ws_size,
                              hipStream_t stream) {
  const float* data  = (const float*)d_in[0];
  const float* W_ih1 = (const float*)d_in[1];
  const float* W_hh1 = (const float*)d_in[2];
  const float* b1    = (const float*)d_in[3];
  const float* W_ih2 = (const float*)d_in[4];
  const float* W_hh2 = (const float*)d_in[5];
  const float* b2    = (const float*)d_in[6];
  const float* W3    = (const float*)d_in[7];
  const float* b3    = (const float*)d_in[8];
  float* outp = (float*)d_out;

  char* ws = (char*)d_ws;
  size_t off = 0;
  float* xp    = (float*)(ws + off); off += (size_t)TCHUNK * GDIM * BATCH * 4;   // 32MB
  float* h1c   = (float*)(ws + off); off += (size_t)TCHUNK * BATCH * HDIM * 4;   // 8MB
  float* h2c   = (float*)(ws + off); off += (size_t)TCHUNK * BATCH * HDIM * 4;   // 8MB
  float* hx1   = (float*)(ws + off); off += 8 * 2 * 2048 * 4;                    // 128KB
  float* hx2   = (float*)(ws + off); off += 8 * 2 * 2048 * 4;
  float* ccur1 = (float*)(ws + off); off += BATCH * HDIM * 4;
  float* ccur2 = (float*)(ws + off); off += BATCH * HDIM * 4;
  unsigned* flg1 = (unsigned*)(ws + off); off += 8 * 64 * 4;                     // 2KB
  unsigned* flg2 = (unsigned*)(ws + off); off += 8 * 64 * 4;
  if (off > ws_size) return;

  hipMemsetAsync(hx1, 0, 8 * 2 * 2048 * 4, stream);
  hipMemsetAsync(hx2, 0, 8 * 2 * 2048 * 4, stream);
  hipMemsetAsync(flg1, 0, 8 * 64 * 4, stream);
  hipMemsetAsync(flg2, 0, 8 * 64 * 4, stream);

  const dim3 pgrid(GDIM / 128, (TCHUNK * BATCH) / 128);
  for (int c = 0; c < NCHUNK; ++c) {
    const float* xin = data + (size_t)c * TCHUNK * BATCH * IDIM;
    proj_kernel<IDIM><<<pgrid, 256, 0, stream>>>(xin, W_ih1, b1, xp);
    scan_kernel<<<NBLK, 256, 0, stream>>>(xp, W_hh1, h1c, hx1, ccur1, flg1,
                                          c * TCHUNK, c == 0);
    proj_kernel<HDIM><<<pgrid, 256, 0, stream>>>(h1c, W_ih2, b2, xp);
    scan_kernel<<<NBLK, 256, 0, stream>>>(xp, W_hh2, h2c, hx2, ccur2, flg2,
                                          c * TCHUNK, c == 0);
    head_kernel<<<(TCHUNK * BATCH) / 4, 256, 0, stream>>>(
        h2c, W3, b3, outp + (size_t)c * TCHUNK * BATCH * ODIM);
  }
}

// Round 5
// 9393.893 us; speedup vs baseline: 4.9075x; 1.0887x over previous
//
#include <hip/hip_runtime.h>
#include <cstdint>
#include <cstddef>

#define TCHUNK 128
#define NCHUNK 8
#define BATCH 32
#define IDIM 128
#define HDIM 512
#define GDIM 2048
#define ODIM 10
#define NBLK 256
#define XPSTEP (GDIM * BATCH)

typedef float f4 __attribute__((ext_vector_type(4)));

// ---- LLC-coherent (sc0 sc1) primitives: correct on any XCD placement ----
__device__ __forceinline__ void llc_store(float* p, float v) {
  asm volatile("global_store_dword %0, %1, off sc0 sc1" :: "v"(p), "v"(v) : "memory");
}
__device__ __forceinline__ void llc_store_u32(unsigned* p, unsigned v) {
  asm volatile("global_store_dword %0, %1, off sc0 sc1" :: "v"(p), "v"(v) : "memory");
}
__device__ __forceinline__ unsigned llc_load_u32(const unsigned* p) {
  unsigned v;
  asm volatile("global_load_dword %0, %1, off sc0 sc1\n\ts_waitcnt vmcnt(0)"
               : "=v"(v) : "v"(p) : "memory");
  return v;
}
// quad (4-lane) butterfly sum via DPP quad_perm — pure VALU
__device__ __forceinline__ float quad_sum(float x) {
  int t = __builtin_amdgcn_update_dpp(0, __float_as_int(x), 0xB1, 0xF, 0xF, true);
  x += __int_as_float(t);
  t = __builtin_amdgcn_update_dpp(0, __float_as_int(x), 0x4E, 0xF, 0xF, true);
  x += __int_as_float(t);
  return x;
}

// ---------------------------------------------------------------------------
// proj: P[tt][n][b] = sum_k X[tt*32+b][k] * W[n][k] + bias[n]
// ---------------------------------------------------------------------------
template<int K>
__launch_bounds__(256, 2)
__global__ void proj_kernel(const float* __restrict__ X,
                            const float* __restrict__ W,
                            const float* __restrict__ bias,
                            float* __restrict__ P) {
  __shared__ float Xs[8][132];
  __shared__ float Ws[8][132];
  const int tid = threadIdx.x;
  const int n0 = blockIdx.x * 128;
  const int m0 = blockIdx.y * 128;
  const int tx = tid & 15, ty = tid >> 4;
  const int lm = tid >> 1;
  const int kq = (tid & 1) * 4;
  float acc[8][8];
#pragma unroll
  for (int i = 0; i < 8; ++i)
#pragma unroll
    for (int j = 0; j < 8; ++j) acc[i][j] = 0.f;

  for (int k0 = 0; k0 < K; k0 += 8) {
    const float4 xv = *(const float4*)&X[(size_t)(m0 + lm) * K + k0 + kq];
    const float4 wv = *(const float4*)&W[(size_t)(n0 + lm) * K + k0 + kq];
    __syncthreads();
    Xs[kq + 0][lm] = xv.x; Xs[kq + 1][lm] = xv.y; Xs[kq + 2][lm] = xv.z; Xs[kq + 3][lm] = xv.w;
    Ws[kq + 0][lm] = wv.x; Ws[kq + 1][lm] = wv.y; Ws[kq + 2][lm] = wv.z; Ws[kq + 3][lm] = wv.w;
    __syncthreads();
#pragma unroll
    for (int kk = 0; kk < 8; ++kk) {
      float a[8], b[8];
      *(float4*)&a[0] = *(const float4*)&Xs[kk][ty * 8];
      *(float4*)&a[4] = *(const float4*)&Xs[kk][ty * 8 + 4];
      *(float4*)&b[0] = *(const float4*)&Ws[kk][tx * 8];
      *(float4*)&b[4] = *(const float4*)&Ws[kk][tx * 8 + 4];
#pragma unroll
      for (int i = 0; i < 8; ++i)
#pragma unroll
        for (int j = 0; j < 8; ++j) acc[i][j] += a[i] * b[j];
    }
  }
  const int mb = m0 + ty * 8;
  const int t  = mb >> 5;
  const int b0 = mb & 31;
#pragma unroll
  for (int j = 0; j < 8; ++j) {
    const int n = n0 + tx * 8 + j;
    const float bj = bias[n];
    float* dst = &P[((size_t)t * GDIM + n) * BATCH + b0];
#pragma unroll
    for (int i = 0; i < 8; ++i) dst[i] = acc[i][j] + bj;
  }
}

// ---------------------------------------------------------------------------
// scan: wave-specialized pipelined LSTM recurrence.
// 256 blocks (1/CU via 85KB LDS). Group g = bid&7 owns batches 4g..4g+3 as 4
// independent chains; block rank = bid>>3 owns h-slots rank*16..+15 (64 W_hh
// rows in VGPRs). Sub-step c computes chain c; wave roles per sub-step c:
//   wave c       : gates + c/h update + h store (LLC)
//   wave (c+3)&3 : vmcnt drain of its stores -> flag (monotonic phase)
//   wave (c+2)&3 : early-poll chain (c+2) flags, async global_load_lds stage
//   wave (c+1)&3 : vmcnt drain of its stage from previous sub-step
// Raw s_barrier + manual lgkmcnt keep stage loads in flight across barriers.
// ---------------------------------------------------------------------------
#define BARRIER() do {                                                      \
    asm volatile("s_waitcnt lgkmcnt(0)" ::: "memory");                      \
    __builtin_amdgcn_sched_barrier(0);                                      \
    __builtin_amdgcn_s_barrier();                                           \
    __builtin_amdgcn_sched_barrier(0);                                      \
  } while (0)

#define STAGE_ISSUE(CH, TPP)                                                \
  {                                                                         \
    const float* slice_ = hxg + ((CH) * 2 + ((TPP) & 1)) * 512;             \
    _Pragma("unroll")                                                       \
    for (int i_ = 0; i_ < 8; ++i_) {                                        \
      __builtin_amdgcn_global_load_lds(                                     \
          (const __attribute__((address_space(1))) unsigned*)(slice_ + karr[i_]), \
          (__attribute__((address_space(3))) unsigned*)&h_s[(CH)][64 * i_], \
          4, 0, 17 /*sc0|sc1*/);                                            \
    }                                                                       \
  }

#define POLL_SPIN(CH, TGT, FV)                                              \
  {                                                                         \
    int guard_ = 0;                                                         \
    while (!__all((int)((FV) >= (unsigned)(TGT))) && ++guard_ < 3000000) {  \
      __builtin_amdgcn_s_sleep(1);                                          \
      (FV) = llc_load_u32(flgg + (CH) * 32 + (l & 31));                     \
    }                                                                       \
  }

#define SUBSTEP(C)                                                          \
  {                                                                         \
    constexpr int c_ = (C);                                                 \
    constexpr int fwv = (c_ + 3) & 3, swv = (c_ + 2) & 3, dwv = (c_ + 1) & 3; \
    const int tpp = t + (c_ >= 2 ? 1 : 0);                                  \
    const bool dostage = (tpp < TCHUNK);                                    \
    unsigned fv0 = 0xFFFFFFFFu;                                             \
    if (w == fwv) {                       /* drain prev update stores, flag */ \
      asm volatile("s_waitcnt vmcnt(0)" ::: "memory");                      \
      if (l == 0)                                                           \
        llc_store_u32(flgg + fwv * 32 + rank,                               \
                      (unsigned)(base + t + (c_ >= 1 ? 1 : 0)));            \
    }                                                                       \
    if (w == swv && dostage) {            /* early-issue poll load */       \
      asm volatile("global_load_dword %0, %1, off sc0 sc1"                  \
                   : "=v"(fv0) : "v"(flgg + swv * 32 + (l & 31)) : "memory"); \
    }                                                                       \
    /* ---- compute partials for chain c_ (all waves) ---- */               \
    {                                                                       \
      float a0 = 0.f, a1 = 0.f, a2 = 0.f, a3 = 0.f;                         \
      const float* hb = &h_s[c_][kb];                                       \
      _Pragma("unroll")                                                     \
      for (int i4 = 0; i4 < 8; ++i4) {                                      \
        const f4 hv = *(const f4*)&hb[4 * (i4 ^ (2 * s4))];                 \
        a0 += wreg[0][i4*4+0]*hv.x + wreg[0][i4*4+1]*hv.y                   \
            + wreg[0][i4*4+2]*hv.z + wreg[0][i4*4+3]*hv.w;                  \
        a1 += wreg[1][i4*4+0]*hv.x + wreg[1][i4*4+1]*hv.y                   \
            + wreg[1][i4*4+2]*hv.z + wreg[1][i4*4+3]*hv.w;                  \
        a2 += wreg[2][i4*4+0]*hv.x + wreg[2][i4*4+1]*hv.y                   \
            + wreg[2][i4*4+2]*hv.z + wreg[2][i4*4+3]*hv.w;                  \
        a3 += wreg[3][i4*4+0]*hv.x + wreg[3][i4*4+1]*hv.y                   \
            + wreg[3][i4*4+2]*hv.z + wreg[3][i4*4+3]*hv.w;                  \
      }                                                                     \
      a0 = quad_sum(a0); a1 = quad_sum(a1);                                 \
      a2 = quad_sum(a2); a3 = quad_sum(a3);                                 \
      const float v01 = (s4 & 1) ? a1 : a0;                                 \
      const float v23 = (s4 & 1) ? a3 : a2;                                 \
      red[w][l] = (s4 & 2) ? v23 : v01;                                     \
    }                                                                       \
    BARRIER();                                                              \
    if (w == c_) {                        /* gates + update + h store */    \
      float pre = red[0][l] + red[1][l] + red[2][l] + red[3][l] + xpv;      \
      const float act = ((l >> 4) == 2) ? tanhf(pre)                        \
                                        : 1.f / (1.f + __expf(-pre));       \
      const int j = l & 15;                                                 \
      const float ig = __shfl(act, j),      fg = __shfl(act, 16 + j);       \
      const float gg = __shfl(act, 32 + j), og = __shfl(act, 48 + j);       \
      if (l < 16) {                                                         \
        c_st = fg * c_st + ig * gg;                                         \
        const float hval = og * tanhf(c_st);                                \
        llc_store(hxg + (c_ * 2 + ((t + 1) & 1)) * 512 + slot16 + l, hval); \
        hout[(size_t)t * (BATCH * HDIM) + (size_t)(g * 4 + c_) * HDIM       \
             + slot16 + l] = hval;                                          \
      }                                                                     \
    }                                                                       \
    if (w == swv && dostage) {            /* confirm poll, async stage */   \
      asm volatile("s_waitcnt vmcnt(0)" ::: "memory");                      \
      POLL_SPIN(swv, base + tpp, fv0);                                      \
      STAGE_ISSUE(swv, tpp);                                                \
      xpv = xp[(size_t)tpp * XPSTEP + xprow];                               \
    }                                                                       \
    if (w == dwv) {                       /* drain its stage from u-1 */    \
      asm volatile("s_waitcnt vmcnt(0)" ::: "memory");                      \
    }                                                                       \
    BARRIER();                                                              \
  }

__launch_bounds__(256, 1)
__global__ void scan_kernel(const float* __restrict__ xp,    // [TCHUNK][GDIM][BATCH]
                            const float* __restrict__ Whh,   // [GDIM][HDIM]
                            float* __restrict__ hout,        // [TCHUNK][BATCH][HDIM]
                            float* __restrict__ hx,          // [8][4][2][512]
                            float* __restrict__ ccur,        // [BATCH][HDIM]
                            unsigned* __restrict__ flg,      // [8][4][32]
                            int base, int first) {
  __shared__ float h_s[4][512];     // per-chain h, XOR-swizzled (k^(((k>>5)&3)<<3))
  __shared__ float red[4][64];      // cross-wave partials
  __shared__ float pad[19456];      // 76KB -> 85KB total -> 1 block/CU

  const int tid = threadIdx.x, bid = blockIdx.x;
  const int g = bid & 7, rank = bid >> 3;
  const int w = tid >> 6, l = tid & 63;
  const int s4 = l & 3, rq = l >> 2;

  float* hxg = hx + g * 4096;
  unsigned* flgg = flg + g * 128;

  // ---- W_hh slice into VGPRs: rows 4rq..4rq+3, k in [kb, kb+32) ----
  float wreg[4][32];
  const int kb = 128 * w + 32 * s4;
#pragma unroll
  for (int r = 0; r < 4; ++r) {
    const int rl = 4 * rq + r;
    const float* wp = &Whh[(size_t)((rl >> 4) * HDIM + rank * 16 + (rl & 15)) * HDIM + kb];
#pragma unroll
    for (int q8 = 0; q8 < 8; ++q8) {
      const f4 v = *(const f4*)&wp[q8 * 4];
      wreg[r][q8 * 4 + 0] = v.x; wreg[r][q8 * 4 + 1] = v.y;
      wreg[r][q8 * 4 + 2] = v.z; wreg[r][q8 * 4 + 3] = v.w;
    }
  }

  // stage permutation (t-invariant): LDS word 64i+l <- slice[karr[i]]
  int karr[8];
#pragma unroll
  for (int i = 0; i < 8; ++i) {
    const int L = 64 * i + l;
    karr[i] = L ^ (((L >> 5) & 3) << 3);
  }

  const int slot16 = rank * 16;
  const size_t xprow = (size_t)((l >> 4) * HDIM + slot16 + (l & 15)) * BATCH + g * 4 + w;
  float c_st = 0.f;
  if (!first && l < 16) c_st = ccur[(size_t)(g * 4 + w) * HDIM + slot16 + l];
  float xpv = 0.f;

  // ---- prologue: waves 0,1 stage chains 0,1 @ t=0 (parity 0) ----
  if (w < 2) {
    unsigned fv = llc_load_u32(flgg + w * 32 + (l & 31));
    POLL_SPIN(w, base, fv);
    STAGE_ISSUE(w, 0);
    xpv = xp[xprow];
    asm volatile("s_waitcnt vmcnt(0)" ::: "memory");
  }
  BARRIER();

#pragma unroll 1
  for (int t = 0; t < TCHUNK; ++t) {
    SUBSTEP(0)
    SUBSTEP(1)
    SUBSTEP(2)
    SUBSTEP(3)
  }

  // epilogue: chain 3's final flag (its flag slot would be sub-step (T,0))
  if (w == 3) {
    asm volatile("s_waitcnt vmcnt(0)" ::: "memory");
    if (l == 0) llc_store_u32(flgg + 3 * 32 + rank, (unsigned)(base + TCHUNK));
  }
  if (l < 16) ccur[(size_t)(g * 4 + w) * HDIM + slot16 + l] = c_st;
  ((volatile float*)pad)[tid] = c_st;   // keep pad allocated (no DCE)
}

// ---------------------------------------------------------------------------
// head: logits = h2 @ W3^T + b3 ; softmax over 10. One wave per row.
// ---------------------------------------------------------------------------
__launch_bounds__(256, 2)
__global__ void head_kernel(const float* __restrict__ h2,
                            const float* __restrict__ W3,
                            const float* __restrict__ b3,
                            float* __restrict__ outp) {
  const int tid = threadIdx.x;
  const int lane = tid & 63;
  const int wv = tid >> 6;
  const int row = blockIdx.x * 4 + wv;
  const float* hrow = &h2[(size_t)row * HDIM];
  float hreg[8];
  *(float4*)&hreg[0] = *(const float4*)&hrow[lane * 8];
  *(float4*)&hreg[4] = *(const float4*)&hrow[lane * 8 + 4];
  float logit[ODIM];
#pragma unroll
  for (int o = 0; o < ODIM; ++o) {
    const float* wrow = &W3[o * HDIM + lane * 8];
    float w[8];
    *(float4*)&w[0] = *(const float4*)&wrow[0];
    *(float4*)&w[4] = *(const float4*)&wrow[4];
    float pp = 0.f;
#pragma unroll
    for (int j = 0; j < 8; ++j) pp += hreg[j] * w[j];
#pragma unroll
    for (int off = 32; off > 0; off >>= 1) pp += __shfl_xor(pp, off);
    logit[o] = pp + b3[o];
  }
  float mx = logit[0];
#pragma unroll
  for (int o = 1; o < ODIM; ++o) mx = fmaxf(mx, logit[o]);
  float ssum = 0.f;
#pragma unroll
  for (int o = 0; o < ODIM; ++o) { logit[o] = __expf(logit[o] - mx); ssum += logit[o]; }
  const float inv = 1.f / ssum;
  if (lane == 0) {
    float* dst = &outp[(size_t)row * ODIM];
#pragma unroll
    for (int o = 0; o < ODIM; ++o) dst[o] = logit[o] * inv;
  }
}

// ---------------------------------------------------------------------------
extern "C" void kernel_launch(void* const* d_in, const int* in_sizes, int n_in,
                              void* d_out, int out_size, void* d_ws, size_t ws_size,
                              hipStream_t stream) {
  const float* data  = (const float*)d_in[0];
  const float* W_ih1 = (const float*)d_in[1];
  const float* W_hh1 = (const float*)d_in[2];
  const float* b1    = (const float*)d_in[3];
  const float* W_ih2 = (const float*)d_in[4];
  const float* W_hh2 = (const float*)d_in[5];
  const float* b2    = (const float*)d_in[6];
  const float* W3    = (const float*)d_in[7];
  const float* b3    = (const float*)d_in[8];
  float* outp = (float*)d_out;

  char* ws = (char*)d_ws;
  size_t off = 0;
  float* xp    = (float*)(ws + off); off += (size_t)TCHUNK * GDIM * BATCH * 4;   // 32MB
  float* h1c   = (float*)(ws + off); off += (size_t)TCHUNK * BATCH * HDIM * 4;   // 8MB
  float* h2c   = (float*)(ws + off); off += (size_t)TCHUNK * BATCH * HDIM * 4;   // 8MB
  float* hx1   = (float*)(ws + off); off += 8 * 4 * 2 * 512 * 4;                 // 128KB
  float* hx2   = (float*)(ws + off); off += 8 * 4 * 2 * 512 * 4;
  float* ccur1 = (float*)(ws + off); off += BATCH * HDIM * 4;
  float* ccur2 = (float*)(ws + off); off += BATCH * HDIM * 4;
  unsigned* flg1 = (unsigned*)(ws + off); off += 8 * 4 * 32 * 4;                 // 4KB
  unsigned* flg2 = (unsigned*)(ws + off); off += 8 * 4 * 32 * 4;
  if (off > ws_size) return;

  hipMemsetAsync(hx1, 0, 8 * 4 * 2 * 512 * 4, stream);
  hipMemsetAsync(hx2, 0, 8 * 4 * 2 * 512 * 4, stream);
  hipMemsetAsync(flg1, 0, 8 * 4 * 32 * 4, stream);
  hipMemsetAsync(flg2, 0, 8 * 4 * 32 * 4, stream);

  const dim3 pgrid(GDIM / 128, (TCHUNK * BATCH) / 128);
  for (int c = 0; c < NCHUNK; ++c) {
    const float* xin = data + (size_t)c * TCHUNK * BATCH * IDIM;
    proj_kernel<IDIM><<<pgrid, 256, 0, stream>>>(xin, W_ih1, b1, xp);
    scan_kernel<<<NBLK, 256, 0, stream>>>(xp, W_hh1, h1c, hx1, ccur1, flg1,
                                          c * TCHUNK, c == 0);
    proj_kernel<HDIM><<<pgrid, 256, 0, stream>>>(h1c, W_ih2, b2, xp);
    scan_kernel<<<NBLK, 256, 0, stream>>>(xp, W_hh2, h2c, hx2, ccur2, flg2,
                                          c * TCHUNK, c == 0);
    head_kernel<<<(TCHUNK * BATCH) / 4, 256, 0, stream>>>(
        h2c, W3, b3, outp + (size_t)c * TCHUNK * BATCH * ODIM);
  }
}

// Round 6
// 8821.867 us; speedup vs baseline: 5.2257x; 1.0648x over previous
//
#include <hip/hip_runtime.h>
#include <cstdint>
#include <cstddef>

#define TCHUNK 128
#define NCHUNK 8
#define BATCH 32
#define IDIM 128
#define HDIM 512
#define GDIM 2048
#define ODIM 10
#define NBLK 256
#define XPSTEP (GDIM * BATCH)
#define SLAB_F 16384            // floats per t-slab: 8 groups x 4 chains x 512
#define SLAB_B (SLAB_F * 4)

typedef float f4 __attribute__((ext_vector_type(4)));
typedef float f2 __attribute__((ext_vector_type(2)));

// LLC-visible store (sc0 sc1): one-way, fire-and-forget, placement-independent
__device__ __forceinline__ void llc_store(float* p, float v) {
  asm volatile("global_store_dword %0, %1, off sc0 sc1" :: "v"(p), "v"(v) : "memory");
}
// quad (4-lane) butterfly sum via DPP quad_perm — pure VALU
__device__ __forceinline__ float quad_sum(float x) {
  int t = __builtin_amdgcn_update_dpp(0, __float_as_int(x), 0xB1, 0xF, 0xF, true);
  x += __int_as_float(t);
  t = __builtin_amdgcn_update_dpp(0, __float_as_int(x), 0x4E, 0xF, 0xF, true);
  x += __int_as_float(t);
  return x;
}

#define BARRIER() do {                                                      \
    asm volatile("s_waitcnt lgkmcnt(0)" ::: "memory");                      \
    __builtin_amdgcn_sched_barrier(0);                                      \
    __builtin_amdgcn_s_barrier();                                           \
    __builtin_amdgcn_sched_barrier(0);                                      \
  } while (0)

// ---------------------------------------------------------------------------
// proj: P[tt][n][b] = sum_k X[tt*32+b][k] * W[n][k] + bias[n]
// float2 accumulators -> v_pk_fma_f32
// ---------------------------------------------------------------------------
template<int K>
__launch_bounds__(256, 2)
__global__ void proj_kernel(const float* __restrict__ X,
                            const float* __restrict__ W,
                            const float* __restrict__ bias,
                            float* __restrict__ P) {
  __shared__ float Xs[8][132];
  __shared__ float Ws[8][132];
  const int tid = threadIdx.x;
  const int n0 = blockIdx.x * 128;
  const int m0 = blockIdx.y * 128;
  const int tx = tid & 15, ty = tid >> 4;
  const int lm = tid >> 1;
  const int kq = (tid & 1) * 4;
  f2 acc2[8][4];
#pragma unroll
  for (int i = 0; i < 8; ++i)
#pragma unroll
    for (int j = 0; j < 4; ++j) acc2[i][j] = (f2){0.f, 0.f};

  for (int k0 = 0; k0 < K; k0 += 8) {
    const float4 xv = *(const float4*)&X[(size_t)(m0 + lm) * K + k0 + kq];
    const float4 wv = *(const float4*)&W[(size_t)(n0 + lm) * K + k0 + kq];
    __syncthreads();
    Xs[kq + 0][lm] = xv.x; Xs[kq + 1][lm] = xv.y; Xs[kq + 2][lm] = xv.z; Xs[kq + 3][lm] = xv.w;
    Ws[kq + 0][lm] = wv.x; Ws[kq + 1][lm] = wv.y; Ws[kq + 2][lm] = wv.z; Ws[kq + 3][lm] = wv.w;
    __syncthreads();
#pragma unroll
    for (int kk = 0; kk < 8; ++kk) {
      float a[8];
      *(float4*)&a[0] = *(const float4*)&Xs[kk][ty * 8];
      *(float4*)&a[4] = *(const float4*)&Xs[kk][ty * 8 + 4];
      f2 b2[4];
#pragma unroll
      for (int jp = 0; jp < 4; ++jp) b2[jp] = *(const f2*)&Ws[kk][tx * 8 + 2 * jp];
#pragma unroll
      for (int i = 0; i < 8; ++i)
#pragma unroll
        for (int jp = 0; jp < 4; ++jp) acc2[i][jp] += b2[jp] * a[i];
    }
  }
  const int mb = m0 + ty * 8;
  const int t  = mb >> 5;
  const int b0 = mb & 31;
#pragma unroll
  for (int j = 0; j < 8; ++j) {
    const int n = n0 + tx * 8 + j;
    const float bj = bias[n];
    float* dst = &P[((size_t)t * GDIM + n) * BATCH + b0];
#pragma unroll
    for (int i = 0; i < 8; ++i)
      dst[i] = ((j & 1) ? acc2[i][j >> 1].y : acc2[i][j >> 1].x) + bj;
  }
}

// ---------------------------------------------------------------------------
// scan: sentinel-exchange LSTM recurrence. 256 blocks, 1/CU (81KB LDS ->
// guaranteed co-residency). Group g=bid&7 owns batches 4g..4g+3; rank=bid>>3
// owns h-slots rank*16..+15 (64 W_hh rows in VGPRs, column-permuted).
// Exchange: write-once per-t slabs hb[t][g][chain][512], sentinel 0xFFFFFFFF
// (negative NaN; h=og*tanh(c) of finite inputs can never produce it).
// Producer: one sc0sc1 store. Consumer: load->reg, test, retry; ds_write
// XOR-swizzled (k' = k ^ ((k>>5)&7)) -> conflict-light reads+writes.
// No flags, no fences, no grid barrier. 3 lgkm-only barriers/step.
// ---------------------------------------------------------------------------
__launch_bounds__(256, 1)
__global__ void scan_kernel(const float* __restrict__ xp,    // [TCHUNK][GDIM][BATCH]
                            const float* __restrict__ Whh,   // [GDIM][HDIM]
                            float* __restrict__ hout,        // [TCHUNK][BATCH][HDIM]
                            float* __restrict__ hb,          // [TCHUNK+1][8][4][512]
                            float* __restrict__ ccur,        // [BATCH][HDIM]
                            int first) {
  __shared__ float h_s[2048];       // [k'][b] swizzled, 4 chains interleaved
  __shared__ float red[1024];       // [w][row l][b4] cross-wave partials
  __shared__ float gate_s[256];
  __shared__ float pad[17408];      // 68KB -> 81KB total -> 1 block/CU

  const int tid = threadIdx.x, bid = blockIdx.x;
  const int g = bid & 7, rank = bid >> 3, slot16 = rank * 16;
  const int w = tid >> 6, l = tid & 63;
  const int s4 = l & 3, rq = l >> 2;
  const int sg = 4 * w + s4;        // k-slice index (16 slices of 32)
  const int cx = sg & 7;            // swizzle key for this slice
  const int kb = 32 * sg;

  // ---- W_hh slice into VGPRs, column-permuted (wreg[r][e] = W[row][kb+(e^cx)])
  // so the hot loop pairs wreg[r][kk] with LINEAR LDS offsets (all indices
  // compile-time -> no scratch).
  float wreg[4][32];
#pragma unroll
  for (int r = 0; r < 4; ++r) {
    const int rl = 4 * rq + r;
    const float* wp = Whh + (size_t)((rl >> 4) * HDIM + slot16 + (rl & 15)) * HDIM + kb;
#pragma unroll
    for (int e = 0; e < 32; ++e) wreg[r][e] = wp[e ^ cx];
  }

  // staging role (t-invariant): chain cl, 8 words at K = 128w + 8m + i
  const int cl = l >> 4, m = l & 15;
  const int sig = (4 * w + (m >> 2)) & 7;       // = (K>>5)&7
  int dsaddr[8];
#pragma unroll
  for (int i = 0; i < 8; ++i)
    dsaddr[i] = 4 * (128 * w + 8 * m + (i ^ sig)) + cl;
  const int srcoff = cl * 512 + 128 * w + 8 * m;

  // gate-cell role (1 pre-activation per thread): q=tid>>6, j, b
  const int qg = tid >> 6, jg = (tid >> 2) & 15, bg = tid & 3;
  const float* xq = xp + (size_t)(qg * HDIM + slot16 + jg) * BATCH + g * 4 + bg;

  // update role (wave 0): cell (slot16+jj, chain bb)
  const int jj = l >> 2, bb = l & 3;

  float c_st = 0.f;
  if (!first && w == 0) c_st = ccur[(size_t)(g * 4 + bb) * HDIM + slot16 + jj];

  const float* hptr = &h_s[128 * sg];

#pragma unroll 1
  for (int tt = 0; tt < TCHUNK; ++tt) {
    // ---- poll + stage h(tt): data is the flag ----
    const float* src = hb + (size_t)tt * SLAB_F + g * 2048 + srcoff;
    f4 va, vb;
    int guard = 0;
    while (true) {
      asm volatile("global_load_dwordx4 %0, %2, off sc0 sc1\n\t"
                   "global_load_dwordx4 %1, %3, off sc0 sc1\n\t"
                   "s_waitcnt vmcnt(0)"
                   : "=&v"(va), "=&v"(vb) : "v"(src), "v"(src + 4) : "memory");
      const bool ok =
          __float_as_uint(va.x) != 0xFFFFFFFFu && __float_as_uint(va.y) != 0xFFFFFFFFu &&
          __float_as_uint(va.z) != 0xFFFFFFFFu && __float_as_uint(va.w) != 0xFFFFFFFFu &&
          __float_as_uint(vb.x) != 0xFFFFFFFFu && __float_as_uint(vb.y) != 0xFFFFFFFFu &&
          __float_as_uint(vb.z) != 0xFFFFFFFFu && __float_as_uint(vb.w) != 0xFFFFFFFFu;
      if (__all(ok) || ++guard > 100000) break;
      __builtin_amdgcn_s_sleep(2);
    }
    h_s[dsaddr[0]] = va.x; h_s[dsaddr[1]] = va.y;
    h_s[dsaddr[2]] = va.z; h_s[dsaddr[3]] = va.w;
    h_s[dsaddr[4]] = vb.x; h_s[dsaddr[5]] = vb.y;
    h_s[dsaddr[6]] = vb.z; h_s[dsaddr[7]] = vb.w;
    const float xpv = xq[(size_t)tt * XPSTEP];
    BARRIER();                                  // h_s ready

    // ---- partials: 4 rows x 4 batches over this thread's 32-k slice ----
    f2 a01[4], a23[4];
#pragma unroll
    for (int r = 0; r < 4; ++r) { a01[r] = (f2){0.f, 0.f}; a23[r] = (f2){0.f, 0.f}; }
#pragma unroll
    for (int kk = 0; kk < 32; ++kk) {
      const f4 hv = *(const f4*)&hptr[4 * kk];
      const f2 h01 = {hv.x, hv.y}, h23 = {hv.z, hv.w};
#pragma unroll
      for (int r = 0; r < 4; ++r) {
        a01[r] += h01 * wreg[r][kk];
        a23[r] += h23 * wreg[r][kk];
      }
    }
#pragma unroll
    for (int r = 0; r < 4; ++r) {
      a01[r].x = quad_sum(a01[r].x); a01[r].y = quad_sum(a01[r].y);
      a23[r].x = quad_sum(a23[r].x); a23[r].y = quad_sum(a23[r].y);
    }
    f2 r01, r23;
    { const f2 v0 = (s4 & 1) ? a01[1] : a01[0];
      const f2 v1 = (s4 & 1) ? a01[3] : a01[2];
      r01 = (s4 & 2) ? v1 : v0;
      const f2 u0 = (s4 & 1) ? a23[1] : a23[0];
      const f2 u1 = (s4 & 1) ? a23[3] : a23[2];
      r23 = (s4 & 2) ? u1 : u0; }
    *(f4*)&red[(w << 8) + 4 * l] = (f4){r01.x, r01.y, r23.x, r23.y};
    BARRIER();                                  // red ready

    // ---- cross-wave reduce + xp + activation (1 cell/thread) ----
    const float pre = red[tid] + red[256 + tid] + red[512 + tid] + red[768 + tid] + xpv;
    gate_s[tid] = (qg == 2) ? tanhf(pre) : 1.f / (1.f + __expf(-pre));
    BARRIER();                                  // gates ready

    // ---- c/h update + one-way exchange store (wave 0) ----
    if (w == 0) {
      const float ig = gate_s[jj * 4 + bb];
      const float fg = gate_s[64 + jj * 4 + bb];
      const float gg = gate_s[128 + jj * 4 + bb];
      const float og = gate_s[192 + jj * 4 + bb];
      c_st = fg * c_st + ig * gg;
      const float hval = og * tanhf(c_st);
      llc_store(hb + (size_t)(tt + 1) * SLAB_F + g * 2048 + bb * 512 + slot16 + jj, hval);
      hout[(size_t)tt * (BATCH * HDIM) + (size_t)(g * 4 + bb) * HDIM + slot16 + jj] = hval;
    }
    // no 4th barrier needed: tt+1 staging writes h_s (reads done before red
    // barrier); gate_s/red next writes are behind tt+1's barriers.
  }
  if (w == 0) ccur[(size_t)(g * 4 + bb) * HDIM + slot16 + jj] = c_st;
  ((volatile float*)pad)[tid] = c_st;           // keep LDS pad allocated
}

// ---------------------------------------------------------------------------
// head: logits = h2 @ W3^T + b3 ; softmax over 10. One wave per row.
// ---------------------------------------------------------------------------
__launch_bounds__(256, 2)
__global__ void head_kernel(const float* __restrict__ h2,
                            const float* __restrict__ W3,
                            const float* __restrict__ b3,
                            float* __restrict__ outp) {
  const int tid = threadIdx.x;
  const int lane = tid & 63;
  const int wv = tid >> 6;
  const int row = blockIdx.x * 4 + wv;
  const float* hrow = &h2[(size_t)row * HDIM];
  float hreg[8];
  *(float4*)&hreg[0] = *(const float4*)&hrow[lane * 8];
  *(float4*)&hreg[4] = *(const float4*)&hrow[lane * 8 + 4];
  float logit[ODIM];
#pragma unroll
  for (int o = 0; o < ODIM; ++o) {
    const float* wrow = &W3[o * HDIM + lane * 8];
    float w[8];
    *(float4*)&w[0] = *(const float4*)&wrow[0];
    *(float4*)&w[4] = *(const float4*)&wrow[4];
    float pp = 0.f;
#pragma unroll
    for (int j = 0; j < 8; ++j) pp += hreg[j] * w[j];
#pragma unroll
    for (int off = 32; off > 0; off >>= 1) pp += __shfl_xor(pp, off);
    logit[o] = pp + b3[o];
  }
  float mx = logit[0];
#pragma unroll
  for (int o = 1; o < ODIM; ++o) mx = fmaxf(mx, logit[o]);
  float ssum = 0.f;
#pragma unroll
  for (int o = 0; o < ODIM; ++o) { logit[o] = __expf(logit[o] - mx); ssum += logit[o]; }
  const float inv = 1.f / ssum;
  if (lane == 0) {
    float* dst = &outp[(size_t)row * ODIM];
#pragma unroll
    for (int o = 0; o < ODIM; ++o) dst[o] = logit[o] * inv;
  }
}

// ---------------------------------------------------------------------------
extern "C" void kernel_launch(void* const* d_in, const int* in_sizes, int n_in,
                              void* d_out, int out_size, void* d_ws, size_t ws_size,
                              hipStream_t stream) {
  const float* data  = (const float*)d_in[0];
  const float* W_ih1 = (const float*)d_in[1];
  const float* W_hh1 = (const float*)d_in[2];
  const float* b1    = (const float*)d_in[3];
  const float* W_ih2 = (const float*)d_in[4];
  const float* W_hh2 = (const float*)d_in[5];
  const float* b2    = (const float*)d_in[6];
  const float* W3    = (const float*)d_in[7];
  const float* b3    = (const float*)d_in[8];
  float* outp = (float*)d_out;

  char* ws = (char*)d_ws;
  size_t off = 0;
  float* xp    = (float*)(ws + off); off += (size_t)TCHUNK * GDIM * BATCH * 4;     // 32MB
  float* h1c   = (float*)(ws + off); off += (size_t)TCHUNK * BATCH * HDIM * 4;     // 8MB
  float* h2c   = (float*)(ws + off); off += (size_t)TCHUNK * BATCH * HDIM * 4;     // 8MB
  float* hb1   = (float*)(ws + off); off += (size_t)(TCHUNK + 1) * SLAB_B;         // 8.45MB
  float* hb2   = (float*)(ws + off); off += (size_t)(TCHUNK + 1) * SLAB_B;
  float* ccur1 = (float*)(ws + off); off += BATCH * HDIM * 4;
  float* ccur2 = (float*)(ws + off); off += BATCH * HDIM * 4;
  if (off > ws_size) return;   // ws too small: bail visibly (output stays poisoned)

  // slab 0 = h(0) = zeros; slabs 1..TCHUNK = sentinel 0xFFFFFFFF
  hipMemsetAsync(hb1, 0x00, SLAB_B, stream);
  hipMemsetAsync((char*)hb1 + SLAB_B, 0xFF, (size_t)TCHUNK * SLAB_B, stream);
  hipMemsetAsync(hb2, 0x00, SLAB_B, stream);
  hipMemsetAsync((char*)hb2 + SLAB_B, 0xFF, (size_t)TCHUNK * SLAB_B, stream);

  const dim3 pgrid(GDIM / 128, (TCHUNK * BATCH) / 128);
  for (int c = 0; c < NCHUNK; ++c) {
    const float* xin = data + (size_t)c * TCHUNK * BATCH * IDIM;
    proj_kernel<IDIM><<<pgrid, 256, 0, stream>>>(xin, W_ih1, b1, xp);
    scan_kernel<<<NBLK, 256, 0, stream>>>(xp, W_hh1, h1c, hb1, ccur1, c == 0);
    if (c < NCHUNK - 1) {   // recycle layer-1 slabs: h(end) -> slab0, re-sentinel
      hipMemcpyAsync(hb1, (char*)hb1 + (size_t)TCHUNK * SLAB_B, SLAB_B,
                     hipMemcpyDeviceToDevice, stream);
      hipMemsetAsync((char*)hb1 + SLAB_B, 0xFF, (size_t)TCHUNK * SLAB_B, stream);
    }
    proj_kernel<HDIM><<<pgrid, 256, 0, stream>>>(h1c, W_ih2, b2, xp);
    scan_kernel<<<NBLK, 256, 0, stream>>>(xp, W_hh2, h2c, hb2, ccur2, c == 0);
    if (c < NCHUNK - 1) {
      hipMemcpyAsync(hb2, (char*)hb2 + (size_t)TCHUNK * SLAB_B, SLAB_B,
                     hipMemcpyDeviceToDevice, stream);
      hipMemsetAsync((char*)hb2 + SLAB_B, 0xFF, (size_t)TCHUNK * SLAB_B, stream);
    }
    head_kernel<<<(TCHUNK * BATCH) / 4, 256, 0, stream>>>(
        h2c, W3, b3, outp + (size_t)c * TCHUNK * BATCH * ODIM);
  }
}